// Round 1
// baseline (15348.758 us; speedup 1.0000x reference)
//
#include <hip/hip_runtime.h>
#include <math.h>

// Problem constants
constexpr int BB  = 16;    // batch
constexpr int TT  = 64;    // time steps
constexpr int TOKN = 4096;
constexpr int DD  = 4096;  // deter
constexpr int HH  = 1024;  // hidden
constexpr int SCN = 1024;  // S*C
constexpr int SN  = 32, CN = 32, AN = 6;
constexpr int FEAT = DD + SCN;           // 5120
constexpr float UNI = 0.01f / 32.0f;     // unimix / C

#define DEVFN __device__ __forceinline__

DEVFN void fma4(float4& acc, float a, float4 w) {
  acc.x = fmaf(a, w.x, acc.x);
  acc.y = fmaf(a, w.y, acc.y);
  acc.z = fmaf(a, w.z, acc.z);
  acc.w = fmaf(a, w.w, acc.w);
}
DEVFN float silu_f(float x) { return x * (1.0f / (1.0f + expf(-x))); }

// ---------------------------------------------------------------------------
// K0: precompute y1tok[t][b][n] = pb1[n] + sum_k tokens[b][t][k] * pW1[k][n]
//     (token half of posterior layer-1, deter-independent). Also zero deter.
// grid 256: bid>>2 = t (64), bid&3 = n-tile(256 wide). 256 thr: wave->4 b rows,
// lane->4 n (float4 weight loads).
// ---------------------------------------------------------------------------
__global__ __launch_bounds__(256) void k0_pre(
    const float* __restrict__ tokens, const float* __restrict__ pW1,
    const float* __restrict__ pb1, float* __restrict__ y1tok,
    float* __restrict__ deter) {
  const int bid = blockIdx.x, tid = threadIdx.x;
  if (bid < 64) {  // deter[16][4096] = 0
    for (int j = tid; j < 1024; j += 256) deter[(size_t)bid * 1024 + j] = 0.0f;
  }
  const int t = bid >> 2, ntile = bid & 3;
  const int lane = tid & 63, wave = tid >> 6;
  const int n = ntile * 256 + lane * 4;
  const int b0 = wave * 4;
  const float* a0 = tokens + ((size_t)(b0 + 0) * TT + t) * TOKN;
  const float* a1 = tokens + ((size_t)(b0 + 1) * TT + t) * TOKN;
  const float* a2 = tokens + ((size_t)(b0 + 2) * TT + t) * TOKN;
  const float* a3 = tokens + ((size_t)(b0 + 3) * TT + t) * TOKN;
  const float* wp = pW1 + n;
  float4 c0 = make_float4(0,0,0,0), c1 = c0, c2 = c0, c3 = c0;
#pragma unroll 4
  for (int k = 0; k < TOKN; ++k) {
    float4 w4 = *(const float4*)(wp + (size_t)k * HH);
    fma4(c0, a0[k], w4); fma4(c1, a1[k], w4);
    fma4(c2, a2[k], w4); fma4(c3, a3[k], w4);
  }
  float4 bi = *(const float4*)(pb1 + n);
  c0.x += bi.x; c0.y += bi.y; c0.z += bi.z; c0.w += bi.w;
  c1.x += bi.x; c1.y += bi.y; c1.z += bi.z; c1.w += bi.w;
  c2.x += bi.x; c2.y += bi.y; c2.z += bi.z; c2.w += bi.w;
  c3.x += bi.x; c3.y += bi.y; c3.z += bi.z; c3.w += bi.w;
  float* o = y1tok + ((size_t)(t * 16 + b0)) * HH + n;
  *(float4*)(o)          = c0;
  *(float4*)(o + HH)     = c1;
  *(float4*)(o + 2 * HH) = c2;
  *(float4*)(o + 3 * HH) = c3;
}

// ---------------------------------------------------------------------------
// K1: QP layer-1 partials. Fused N=2048: n<1024 = prior (deter@qW1),
// n>=1024 = posterior deter-half (deter@pW1[4096:]). ksplit=32 (kchunk 128).
// grid 256: bid&31 = v (k-chunk), bid>>5 = n-tile (0..7). part1[v][b][2048].
// ---------------------------------------------------------------------------
__global__ __launch_bounds__(256) void k_qp1(
    const float* __restrict__ deter, const float* __restrict__ qW1,
    const float* __restrict__ pW1, float* __restrict__ part1,
    int do_q, int do_p) {
  const int bid = blockIdx.x;
  const int v = bid & 31, ntile = bid >> 5;
  const int isP = ntile >= 4;
  if (isP ? !do_p : !do_q) return;
  const int lane = threadIdx.x & 63, wave = threadIdx.x >> 6;
  const int b0 = wave * 4;
  const int n_glob = ntile * 256 + lane * 4;
  const int n_loc = isP ? (n_glob - 1024) : n_glob;
  const float* W = isP ? (pW1 + (size_t)DD * HH) : qW1;
  const float* wp = W + (size_t)(v * 128) * HH + n_loc;
  const float* x0 = deter + (size_t)b0 * DD + v * 128;
  float4 c0 = make_float4(0,0,0,0), c1 = c0, c2 = c0, c3 = c0;
#pragma unroll 4
  for (int kk = 0; kk < 128; ++kk) {
    float4 w4 = *(const float4*)(wp + (size_t)kk * HH);
    fma4(c0, x0[kk], w4);
    fma4(c1, x0[DD + kk], w4);
    fma4(c2, x0[2 * DD + kk], w4);
    fma4(c3, x0[3 * DD + kk], w4);
  }
  float* o = part1 + ((size_t)(v * 16 + b0)) * 2048 + n_glob;
  *(float4*)(o)        = c0;
  *(float4*)(o + 2048) = c1;
  *(float4*)(o + 4096) = c2;
  *(float4*)(o + 6144) = c3;
}

// ---------------------------------------------------------------------------
// K_mid: layers 2 / out. x[16][2048] (q|p halves), K=1024 each head,
// ksplit=8, grid 64: bid&7 = v, bid>>3 = n-tile. part[v][b][2048].
// ---------------------------------------------------------------------------
__global__ __launch_bounds__(256) void k_mid(
    const float* __restrict__ x, const float* __restrict__ Wq,
    const float* __restrict__ Wp, float* __restrict__ part,
    int do_q, int do_p) {
  const int bid = blockIdx.x;
  const int v = bid & 7, ntile = bid >> 3;
  const int isP = ntile >= 4;
  if (isP ? !do_p : !do_q) return;
  const int lane = threadIdx.x & 63, wave = threadIdx.x >> 6;
  const int b0 = wave * 4;
  const int n_glob = ntile * 256 + lane * 4;
  const int n_loc = isP ? (n_glob - 1024) : n_glob;
  const float* wp = (isP ? Wp : Wq) + (size_t)(v * 128) * HH + n_loc;
  const float* xb = x + (size_t)b0 * 2048 + (isP ? 1024 : 0) + v * 128;
  float4 c0 = make_float4(0,0,0,0), c1 = c0, c2 = c0, c3 = c0;
#pragma unroll 4
  for (int kk = 0; kk < 128; ++kk) {
    float4 w4 = *(const float4*)(wp + (size_t)kk * HH);
    fma4(c0, xb[kk], w4);
    fma4(c1, xb[2048 + kk], w4);
    fma4(c2, xb[4096 + kk], w4);
    fma4(c3, xb[6144 + kk], w4);
  }
  float* o = part + ((size_t)(v * 16 + b0)) * 2048 + n_glob;
  *(float4*)(o)        = c0;
  *(float4*)(o + 2048) = c1;
  *(float4*)(o + 4096) = c2;
  *(float4*)(o + 6144) = c3;
}

// ---------------------------------------------------------------------------
// K_red: reduce ksplit partials + bias (or precomputed token base), then
// LayerNorm (two-pass, matching reference) + SiLU. grid 32: bid&15 = b,
// bid>>4 = head (0=q prior, 1=p posterior). 256 thr x 4 elems.
// ---------------------------------------------------------------------------
__global__ __launch_bounds__(256) void k_red(
    const float* __restrict__ part, int nv,
    const float* __restrict__ qbias, const float* __restrict__ pbias,
    const float* __restrict__ ytokrow,  // y1tok + i*16*1024 for layer1, else null
    const float* __restrict__ qg, const float* __restrict__ qB,
    const float* __restrict__ pg, const float* __restrict__ pB,
    float* __restrict__ xout, int do_q, int do_p) {
  const int b = blockIdx.x & 15, head = blockIdx.x >> 4;
  if (head ? !do_p : !do_q) return;
  const int tid = threadIdx.x;
  __shared__ float red[256];
  __shared__ float m_sh, r_sh;
  float y[4];
#pragma unroll
  for (int j = 0; j < 4; ++j) {
    const int n = tid + j * 256;
    float s;
    if (head) s = ytokrow ? ytokrow[(size_t)b * HH + n] : pbias[n];
    else      s = qbias[n];
    for (int v = 0; v < nv; ++v)
      s += part[((size_t)(v * 16 + b)) * 2048 + head * 1024 + n];
    y[j] = s;
  }
  float sum = y[0] + y[1] + y[2] + y[3];
  red[tid] = sum; __syncthreads();
  for (int st = 128; st > 0; st >>= 1) {
    if (tid < st) red[tid] += red[tid + st];
    __syncthreads();
  }
  if (tid == 0) m_sh = red[0] * (1.0f / 1024.0f);
  __syncthreads();
  const float m = m_sh;
  float vs = 0.0f;
#pragma unroll
  for (int j = 0; j < 4; ++j) { float d = y[j] - m; vs = fmaf(d, d, vs); }
  red[tid] = vs; __syncthreads();
  for (int st = 128; st > 0; st >>= 1) {
    if (tid < st) red[tid] += red[tid + st];
    __syncthreads();
  }
  if (tid == 0) r_sh = 1.0f / sqrtf(red[0] * (1.0f / 1024.0f) + 1e-5f);
  __syncthreads();
  const float rs = r_sh;
  const float* g  = head ? pg : qg;
  const float* Bv = head ? pB : qB;
#pragma unroll
  for (int j = 0; j < 4; ++j) {
    const int n = tid + j * 256;
    float t = (y[j] - m) * rs * g[n] + Bv[n];
    xout[(size_t)b * 2048 + head * 1024 + n] = silu_f(t);
  }
}

// ---------------------------------------------------------------------------
// K_samp: per-b block. Reduce logits (bias + 8 partials), gumbel-max sample
// prior (step i-1) -> write one-hot into feat, sample posterior (step i) ->
// one-hot gather through gW + act rows + LN + SiLU -> xg (GRU input).
// ---------------------------------------------------------------------------
__global__ __launch_bounds__(256) void k_samp(
    const float* __restrict__ part3,
    const float* __restrict__ qbo, const float* __restrict__ pbo,
    const float* __restrict__ g_prior, const float* __restrict__ g_post,
    const float* __restrict__ actions, const float* __restrict__ gW,
    const float* __restrict__ gb, const float* __restrict__ gg,
    const float* __restrict__ gB, float* __restrict__ out,
    float* __restrict__ xg, int i, int do_q, int do_p) {
  const int b = blockIdx.x, tid = threadIdx.x;
  __shared__ float lq[1024], lp[1024];
  __shared__ int idxp[32];
  __shared__ float red[256];
  __shared__ float m_sh, r_sh;

#pragma unroll
  for (int j = 0; j < 4; ++j) {
    const int n = tid + j * 256;
    if (do_q) {
      float s = qbo[n];
      for (int v = 0; v < 8; ++v) s += part3[((size_t)(v * 16 + b)) * 2048 + n];
      lq[n] = s;
    }
    if (do_p) {
      float s = pbo[n];
      for (int v = 0; v < 8; ++v) s += part3[((size_t)(v * 16 + b)) * 2048 + 1024 + n];
      lp[n] = s;
    }
  }
  __syncthreads();

  if (do_q && tid < 32) {  // prior sample for step i-1, write one-hot to feat
    const int s_ = tid;
    const float* l = lq + s_ * CN;
    const float* g = g_prior + (((size_t)(i - 1) * BB + b) * SN + s_) * CN;
    float mx = l[0];
    for (int c = 1; c < CN; ++c) mx = fmaxf(mx, l[c]);
    float Z = 0.0f;
    for (int c = 0; c < CN; ++c) Z += expf(l[c] - mx);
    float best = -1e30f; int bi = 0; float pbest = 0.0f;
    for (int c = 0; c < CN; ++c) {
      float p = 0.99f * (expf(l[c] - mx) / Z) + UNI;
      float sc = logf(p) + g[c];
      if (sc > best) { best = sc; bi = c; pbest = p; }
    }
    float* o = out + ((size_t)b * TT + (i - 1)) * FEAT + DD + s_ * CN;
    for (int c = 0; c < CN; ++c)
      o[c] = (c == bi) ? ((1.0f - pbest) + pbest) : 0.0f;
  }
  if (do_p && tid >= 32 && tid < 64) {  // posterior sample for step i
    const int s_ = tid - 32;
    const float* l = lp + s_ * CN;
    const float* g = g_post + (((size_t)i * BB + b) * SN + s_) * CN;
    float mx = l[0];
    for (int c = 1; c < CN; ++c) mx = fmaxf(mx, l[c]);
    float Z = 0.0f;
    for (int c = 0; c < CN; ++c) Z += expf(l[c] - mx);
    float best = -1e30f; int bi = 0;
    for (int c = 0; c < CN; ++c) {
      float p = 0.99f * (expf(l[c] - mx) / Z) + UNI;
      float sc = logf(p) + g[c];
      if (sc > best) { best = sc; bi = c; }
    }
    idxp[s_] = bi;
  }
  __syncthreads();

  if (do_p) {  // gather one-hot @ gW + act rows, LN + SiLU -> xg
    float av[AN];
#pragma unroll
    for (int aa = 0; aa < AN; ++aa)
      av[aa] = actions[((size_t)b * TT + i) * AN + aa];
    float xv[4];
#pragma unroll
    for (int j = 0; j < 4; ++j) {
      const int h = tid + j * 256;
      float s = gb[h];
      for (int ss = 0; ss < SN; ++ss)
        s += gW[(size_t)(ss * CN + idxp[ss]) * HH + h];
#pragma unroll
      for (int aa = 0; aa < AN; ++aa)
        s = fmaf(av[aa], gW[(size_t)(SCN + aa) * HH + h], s);
      xv[j] = s;
    }
    float sum = xv[0] + xv[1] + xv[2] + xv[3];
    red[tid] = sum; __syncthreads();
    for (int st = 128; st > 0; st >>= 1) {
      if (tid < st) red[tid] += red[tid + st];
      __syncthreads();
    }
    if (tid == 0) m_sh = red[0] * (1.0f / 1024.0f);
    __syncthreads();
    const float m = m_sh;
    float vs = 0.0f;
#pragma unroll
    for (int j = 0; j < 4; ++j) { float d = xv[j] - m; vs = fmaf(d, d, vs); }
    red[tid] = vs; __syncthreads();
    for (int st = 128; st > 0; st >>= 1) {
      if (tid < st) red[tid] += red[tid + st];
      __syncthreads();
    }
    if (tid == 0) r_sh = 1.0f / sqrtf(red[0] * (1.0f / 1024.0f) + 1e-5f);
    __syncthreads();
    const float rs = r_sh;
#pragma unroll
    for (int j = 0; j < 4; ++j) {
      const int h = tid + j * 256;
      float t = (xv[j] - m) * rs * gg[h] + gB[h];
      xg[(size_t)b * HH + h] = silu_f(t);
    }
  }
}

// ---------------------------------------------------------------------------
// K_g: GRU gate GEMMs. h=[xg(1024)|deter(4096)], K=5120, N=4096, z & c.
// grid 256: bid&15 = v (kchunk 320), bid>>4 = n-tile (256 wide).
// partG[(v*2+zc)*16+b][4096].
// ---------------------------------------------------------------------------
__global__ __launch_bounds__(256) void k_g(
    const float* __restrict__ xg, const float* __restrict__ deter,
    const float* __restrict__ gWz, const float* __restrict__ gWc,
    float* __restrict__ partG) {
  const int bid = blockIdx.x;
  const int v = bid & 15, ntile = bid >> 4;
  const int lane = threadIdx.x & 63, wave = threadIdx.x >> 6;
  const int b0 = wave * 4;
  const int n = ntile * 256 + lane * 4;
  const float* wz = gWz + (size_t)(v * 320) * DD + n;
  const float* wc = gWc + (size_t)(v * 320) * DD + n;
  float4 z0 = make_float4(0,0,0,0), z1 = z0, z2 = z0, z3 = z0;
  float4 c0 = z0, c1 = z0, c2 = z0, c3 = z0;
#pragma unroll 2
  for (int kk = 0; kk < 320; ++kk) {
    const int kg = v * 320 + kk;
    float4 wz4 = *(const float4*)(wz + (size_t)kk * DD);
    float4 wc4 = *(const float4*)(wc + (size_t)kk * DD);
    float h0, h1, h2, h3;
    if (kg < HH) {
      h0 = xg[(size_t)(b0 + 0) * HH + kg];
      h1 = xg[(size_t)(b0 + 1) * HH + kg];
      h2 = xg[(size_t)(b0 + 2) * HH + kg];
      h3 = xg[(size_t)(b0 + 3) * HH + kg];
    } else {
      const int kd = kg - HH;
      h0 = deter[(size_t)(b0 + 0) * DD + kd];
      h1 = deter[(size_t)(b0 + 1) * DD + kd];
      h2 = deter[(size_t)(b0 + 2) * DD + kd];
      h3 = deter[(size_t)(b0 + 3) * DD + kd];
    }
    fma4(z0, h0, wz4); fma4(z1, h1, wz4); fma4(z2, h2, wz4); fma4(z3, h3, wz4);
    fma4(c0, h0, wc4); fma4(c1, h1, wc4); fma4(c2, h2, wc4); fma4(c3, h3, wc4);
  }
  float* oz = partG + ((size_t)((v * 2 + 0) * 16 + b0)) * DD + n;
  float* oc = partG + ((size_t)((v * 2 + 1) * 16 + b0)) * DD + n;
  *(float4*)(oz)          = z0;
  *(float4*)(oz + DD)     = z1;
  *(float4*)(oz + 2 * DD) = z2;
  *(float4*)(oz + 3 * DD) = z3;
  *(float4*)(oc)          = c0;
  *(float4*)(oc + DD)     = c1;
  *(float4*)(oc + 2 * DD) = c2;
  *(float4*)(oc + 3 * DD) = c3;
}

// ---------------------------------------------------------------------------
// K_r: reduce GRU partials, deter = (1-z)*deter + z*tanh(c), write feat deter.
// grid 64: bid>>2 = b, bid&3 = quarter of 4096.
// ---------------------------------------------------------------------------
__global__ __launch_bounds__(256) void k_r(
    const float* __restrict__ partG, const float* __restrict__ gbz,
    const float* __restrict__ gbc, float* __restrict__ deter,
    float* __restrict__ out, int i) {
  const int b = blockIdx.x >> 2, q = blockIdx.x & 3;
  const int tid = threadIdx.x;
#pragma unroll
  for (int j = 0; j < 4; ++j) {
    const int n = q * 1024 + j * 256 + tid;
    float zs = gbz[n], cs = gbc[n];
    for (int v = 0; v < 16; ++v) {
      zs += partG[((size_t)((v * 2 + 0) * 16 + b)) * DD + n];
      cs += partG[((size_t)((v * 2 + 1) * 16 + b)) * DD + n];
    }
    const float z = 1.0f / (1.0f + expf(-zs));
    const float cd = tanhf(cs);
    const float dn = (1.0f - z) * deter[(size_t)b * DD + n] + z * cd;
    deter[(size_t)b * DD + n] = dn;
    out[((size_t)b * TT + i) * FEAT + n] = dn;
  }
}

// ---------------------------------------------------------------------------
extern "C" void kernel_launch(void* const* d_in, const int* in_sizes, int n_in,
                              void* d_out, int out_size, void* d_ws,
                              size_t ws_size, hipStream_t stream) {
  (void)in_sizes; (void)n_in; (void)out_size; (void)ws_size;
  const float* tokens  = (const float*)d_in[0];
  const float* actions = (const float*)d_in[1];
  const float* g_post  = (const float*)d_in[2];
  const float* g_prior = (const float*)d_in[3];
  const float* pW1 = (const float*)d_in[4];
  const float* pb1 = (const float*)d_in[5];
  const float* pg1 = (const float*)d_in[6];
  const float* pB1 = (const float*)d_in[7];
  const float* pW2 = (const float*)d_in[8];
  const float* pb2 = (const float*)d_in[9];
  const float* pg2 = (const float*)d_in[10];
  const float* pB2 = (const float*)d_in[11];
  const float* pWo = (const float*)d_in[12];
  const float* pbo = (const float*)d_in[13];
  const float* qW1 = (const float*)d_in[14];
  const float* qb1 = (const float*)d_in[15];
  const float* qg1 = (const float*)d_in[16];
  const float* qB1 = (const float*)d_in[17];
  const float* qW2 = (const float*)d_in[18];
  const float* qb2 = (const float*)d_in[19];
  const float* qg2 = (const float*)d_in[20];
  const float* qB2 = (const float*)d_in[21];
  const float* qWo = (const float*)d_in[22];
  const float* qbo = (const float*)d_in[23];
  const float* gW  = (const float*)d_in[24];
  const float* gb  = (const float*)d_in[25];
  const float* gg  = (const float*)d_in[26];
  const float* gB  = (const float*)d_in[27];
  const float* gWz = (const float*)d_in[28];
  const float* gbz = (const float*)d_in[29];
  const float* gWc = (const float*)d_in[30];
  const float* gbc = (const float*)d_in[31];
  float* out = (float*)d_out;

  // Workspace layout (floats)
  float* ws    = (float*)d_ws;
  float* y1tok = ws + 0;        // [64][16][1024]   = 1,048,576
  float* part1 = ws + 1048576;  // [32][16][2048]   = 1,048,576
  float* part2 = ws + 2097152;  // [8][16][2048]    =   262,144
  float* part3 = ws + 2359296;  // [8][16][2048]    =   262,144
  float* x1    = ws + 2621440;  // [16][2048]
  float* x2    = ws + 2654208;  // [16][2048]
  float* xg    = ws + 2686976;  // [16][1024]
  float* deter = ws + 2703360;  // [16][4096]
  float* partG = ws + 2768896;  // [16][2][16][4096] = 2,097,152
  // total 4,866,048 floats ~= 18.6 MiB

  k0_pre<<<256, 256, 0, stream>>>(tokens, pW1, pb1, y1tok, deter);

  // iteration i: prior head for step i-1 (do_q) || posterior head + GRU for
  // step i (do_p). deter holds deter_{i-1} at iteration entry.
  for (int i = 0; i <= TT; ++i) {
    const int do_q = (i >= 1) ? 1 : 0;
    const int do_p = (i <= TT - 1) ? 1 : 0;
    const float* ytokrow = y1tok + (size_t)((i <= 63) ? i : 63) * 16 * HH;

    k_qp1<<<256, 256, 0, stream>>>(deter, qW1, pW1, part1, do_q, do_p);
    k_red<<<32, 256, 0, stream>>>(part1, 32, qb1, pb1, ytokrow,
                                  qg1, qB1, pg1, pB1, x1, do_q, do_p);
    k_mid<<<64, 256, 0, stream>>>(x1, qW2, pW2, part2, do_q, do_p);
    k_red<<<32, 256, 0, stream>>>(part2, 8, qb2, pb2, nullptr,
                                  qg2, qB2, pg2, pB2, x2, do_q, do_p);
    k_mid<<<64, 256, 0, stream>>>(x2, qWo, pWo, part3, do_q, do_p);
    k_samp<<<16, 256, 0, stream>>>(part3, qbo, pbo, g_prior, g_post, actions,
                                   gW, gb, gg, gB, out, xg, i, do_q, do_p);
    if (do_p) {
      k_g<<<256, 256, 0, stream>>>(xg, deter, gWz, gWc, partG);
      k_r<<<64, 256, 0, stream>>>(partG, gbz, gbc, deter, out, i);
    }
  }
}

// Round 2
// 9748.951 us; speedup vs baseline: 1.5744x; 1.5744x over previous
//
#include <hip/hip_runtime.h>
#include <math.h>

constexpr int BB  = 16;
constexpr int TT  = 64;
constexpr int TOKN = 4096;
constexpr int DD  = 4096;
constexpr int HH  = 1024;
constexpr int SCN = 1024;
constexpr int SN  = 32, CN = 32, AN = 6;
constexpr int FEAT = DD + SCN;        // 5120
constexpr float UNI = 0.01f / 32.0f;

#define DEVFN __device__ __forceinline__

DEVFN float4 z4() { return make_float4(0.f, 0.f, 0.f, 0.f); }
DEVFN float4 ld4(const float* p) { return *(const float4*)p; }
DEVFN void st4(float* p, float4 v) { *(float4*)p = v; }
DEVFN void add4(float4& a, float4 b) { a.x += b.x; a.y += b.y; a.z += b.z; a.w += b.w; }
DEVFN void fma4(float4& acc, float a, float4 w) {
  acc.x = fmaf(a, w.x, acc.x);
  acc.y = fmaf(a, w.y, acc.y);
  acc.z = fmaf(a, w.z, acc.z);
  acc.w = fmaf(a, w.w, acc.w);
}
DEVFN float silu_f(float x) { return x * (1.0f / (1.0f + expf(-x))); }

// 64-lane reduce-sum via shuffle
DEVFN float wave_sum(float v) {
#pragma unroll
  for (int m = 1; m < 64; m <<= 1) v += __shfl_xor(v, m);
  return v;
}

// ---------------------------------------------------------------------------
// K0: y1tok[t][b][n] = pb1[n] + tokens[b][t][:] @ pW1[0:4096][n]. Also zero
// hcat deter-half (deter0 = 0). grid 256: bid>>2=t, bid&3=ntile(256).
// ---------------------------------------------------------------------------
__global__ __launch_bounds__(256) void k0_pre(
    const float* __restrict__ tokens, const float* __restrict__ pW1,
    const float* __restrict__ pb1, float* __restrict__ y1tok,
    float* __restrict__ hcat) {
  const int bid = blockIdx.x, tid = threadIdx.x;
  if (bid < 64) {  // hcat[b][1024:5120] = 0
    const int b = bid >> 2, q = bid & 3;
    st4(hcat + (size_t)b * FEAT + 1024 + q * 1024 + tid * 4, z4());
  }
  const int t = bid >> 2, nt = bid & 3;
  const int lane = tid & 63, wave = tid >> 6, b0 = wave * 4;
  const int n = nt * 256 + lane * 4;
  const float* a0 = tokens + ((size_t)(b0 + 0) * TT + t) * TOKN;
  const float* a1 = tokens + ((size_t)(b0 + 1) * TT + t) * TOKN;
  const float* a2 = tokens + ((size_t)(b0 + 2) * TT + t) * TOKN;
  const float* a3 = tokens + ((size_t)(b0 + 3) * TT + t) * TOKN;
  const float* wp = pW1 + n;
  float4 c0 = z4(), c1 = z4(), c2 = z4(), c3 = z4();
#pragma unroll 4
  for (int k = 0; k < TOKN; k += 4) {
    float4 x0 = ld4(a0 + k), x1 = ld4(a1 + k), x2 = ld4(a2 + k), x3 = ld4(a3 + k);
    float4 w0 = ld4(wp + (size_t)(k + 0) * HH);
    float4 w1 = ld4(wp + (size_t)(k + 1) * HH);
    float4 w2 = ld4(wp + (size_t)(k + 2) * HH);
    float4 w3 = ld4(wp + (size_t)(k + 3) * HH);
    fma4(c0, x0.x, w0); fma4(c1, x1.x, w0); fma4(c2, x2.x, w0); fma4(c3, x3.x, w0);
    fma4(c0, x0.y, w1); fma4(c1, x1.y, w1); fma4(c2, x2.y, w1); fma4(c3, x3.y, w1);
    fma4(c0, x0.z, w2); fma4(c1, x1.z, w2); fma4(c2, x2.z, w2); fma4(c3, x3.z, w2);
    fma4(c0, x0.w, w3); fma4(c1, x1.w, w3); fma4(c2, x2.w, w3); fma4(c3, x3.w, w3);
  }
  float4 bi = ld4(pb1 + n);
  add4(c0, bi); add4(c1, bi); add4(c2, bi); add4(c3, bi);
  float* o = y1tok + ((size_t)t * 16 + b0) * HH + n;
  st4(o, c0); st4(o + HH, c1); st4(o + 2 * HH, c2); st4(o + 3 * HH, c3);
}

// ---------------------------------------------------------------------------
// K_qp1: layer-1 deter GEMM for prior (n<1024, qW1) and posterior deter-half
// (n>=1024, pW1[4096:]). grid 512: v=bid&63 (kchunk 64), ntile=bid>>6 (8).
// part1[v][b][2048].
// ---------------------------------------------------------------------------
__global__ __launch_bounds__(256) void k_qp1(
    const float* __restrict__ hcat, const float* __restrict__ qW1,
    const float* __restrict__ pW1, float* __restrict__ part1,
    int do_q, int do_p) {
  const int bid = blockIdx.x;
  const int v = bid & 63, nt = bid >> 6;
  const int isP = nt >= 4;
  if (isP ? !do_p : !do_q) return;
  const int lane = threadIdx.x & 63, wave = threadIdx.x >> 6, b0 = wave * 4;
  const int n = nt * 256 + lane * 4;
  const int n_loc = isP ? (n - 1024) : n;
  const float* wp = (isP ? pW1 + (size_t)TOKN * HH : qW1) + (size_t)(v * 64) * HH + n_loc;
  const float* ap = hcat + (size_t)b0 * FEAT + 1024 + v * 64;
  float4 c0 = z4(), c1 = z4(), c2 = z4(), c3 = z4();
#pragma unroll 4
  for (int k = 0; k < 64; k += 4) {
    float4 x0 = ld4(ap + k);
    float4 x1 = ld4(ap + FEAT + k);
    float4 x2 = ld4(ap + 2 * FEAT + k);
    float4 x3 = ld4(ap + 3 * FEAT + k);
    float4 w0 = ld4(wp + (size_t)(k + 0) * HH);
    float4 w1 = ld4(wp + (size_t)(k + 1) * HH);
    float4 w2 = ld4(wp + (size_t)(k + 2) * HH);
    float4 w3 = ld4(wp + (size_t)(k + 3) * HH);
    fma4(c0, x0.x, w0); fma4(c1, x1.x, w0); fma4(c2, x2.x, w0); fma4(c3, x3.x, w0);
    fma4(c0, x0.y, w1); fma4(c1, x1.y, w1); fma4(c2, x2.y, w1); fma4(c3, x3.y, w1);
    fma4(c0, x0.z, w2); fma4(c1, x1.z, w2); fma4(c2, x2.z, w2); fma4(c3, x3.z, w2);
    fma4(c0, x0.w, w3); fma4(c1, x1.w, w3); fma4(c2, x2.w, w3); fma4(c3, x3.w, w3);
  }
  float* o = part1 + ((size_t)v * 16 + b0) * 2048 + n;
  st4(o, c0); st4(o + 2048, c1); st4(o + 4096, c2); st4(o + 6144, c3);
}

// ---------------------------------------------------------------------------
// K_mid: layers 2/out, K=1024 per head. grid 256: v=bid&31 (kchunk 32),
// ntile=bid>>5 (8). part[v][b][2048].
// ---------------------------------------------------------------------------
__global__ __launch_bounds__(256) void k_mid(
    const float* __restrict__ x, const float* __restrict__ Wq,
    const float* __restrict__ Wp, float* __restrict__ part,
    int do_q, int do_p) {
  const int bid = blockIdx.x;
  const int v = bid & 31, nt = bid >> 5;
  const int isP = nt >= 4;
  if (isP ? !do_p : !do_q) return;
  const int lane = threadIdx.x & 63, wave = threadIdx.x >> 6, b0 = wave * 4;
  const int n = nt * 256 + lane * 4;
  const int n_loc = isP ? (n - 1024) : n;
  const float* wp = (isP ? Wp : Wq) + (size_t)(v * 32) * HH + n_loc;
  const float* ap = x + (size_t)b0 * 2048 + (isP ? 1024 : 0) + v * 32;
#pragma unroll
  for (int dummy = 0; dummy < 1; ++dummy) {}
  float4 c0 = z4(), c1 = z4(), c2 = z4(), c3 = z4();
#pragma unroll
  for (int k = 0; k < 32; k += 4) {
    float4 x0 = ld4(ap + k);
    float4 x1 = ld4(ap + 2048 + k);
    float4 x2 = ld4(ap + 4096 + k);
    float4 x3 = ld4(ap + 6144 + k);
    float4 w0 = ld4(wp + (size_t)(k + 0) * HH);
    float4 w1 = ld4(wp + (size_t)(k + 1) * HH);
    float4 w2 = ld4(wp + (size_t)(k + 2) * HH);
    float4 w3 = ld4(wp + (size_t)(k + 3) * HH);
    fma4(c0, x0.x, w0); fma4(c1, x1.x, w0); fma4(c2, x2.x, w0); fma4(c3, x3.x, w0);
    fma4(c0, x0.y, w1); fma4(c1, x1.y, w1); fma4(c2, x2.y, w1); fma4(c3, x3.y, w1);
    fma4(c0, x0.z, w2); fma4(c1, x1.z, w2); fma4(c2, x2.z, w2); fma4(c3, x3.z, w2);
    fma4(c0, x0.w, w3); fma4(c1, x1.w, w3); fma4(c2, x2.w, w3); fma4(c3, x3.w, w3);
  }
  float* o = part + ((size_t)v * 16 + b0) * 2048 + n;
  st4(o, c0); st4(o + 2048, c1); st4(o + 4096, c2); st4(o + 6144, c3);
}

// ---------------------------------------------------------------------------
// K_red<NV>: reduce k-split partials + bias/token-base, LayerNorm + SiLU.
// grid 32: bid&15=b, bid>>4=head (0=q,1=p). thread -> 4 consecutive n (f4).
// ---------------------------------------------------------------------------
template <int NV>
__global__ __launch_bounds__(256) void k_red(
    const float* __restrict__ part,
    const float* __restrict__ qbias, const float* __restrict__ pbias,
    const float* __restrict__ ytokrow,
    const float* __restrict__ qg, const float* __restrict__ qB,
    const float* __restrict__ pg, const float* __restrict__ pB,
    float* __restrict__ xout, int do_q, int do_p) {
  const int b = blockIdx.x & 15, head = blockIdx.x >> 4;
  if (head ? !do_p : !do_q) return;
  const int tid = threadIdx.x, lane = tid & 63, wave = tid >> 6;
  const int n = tid * 4;
  __shared__ float sm[8];
  float4 y;
  if (head) y = ytokrow ? ld4(ytokrow + (size_t)b * HH + n) : ld4(pbias + n);
  else      y = ld4(qbias + n);
#pragma unroll 8
  for (int v = 0; v < NV; ++v)
    add4(y, ld4(part + ((size_t)v * 16 + b) * 2048 + head * 1024 + n));
  float s = wave_sum(y.x + y.y + y.z + y.w);
  if (lane == 0) sm[wave] = s;
  __syncthreads();
  const float mean = (sm[0] + sm[1] + sm[2] + sm[3]) * (1.0f / 1024.0f);
  float dx = y.x - mean, dy = y.y - mean, dz = y.z - mean, dw = y.w - mean;
  float vs = wave_sum(dx * dx + dy * dy + dz * dz + dw * dw);
  if (lane == 0) sm[4 + wave] = vs;
  __syncthreads();
  const float rstd = 1.0f / sqrtf((sm[4] + sm[5] + sm[6] + sm[7]) * (1.0f / 1024.0f) + 1e-5f);
  float4 g4 = ld4((head ? pg : qg) + n);
  float4 B4 = ld4((head ? pB : qB) + n);
  float4 r;
  r.x = silu_f(dx * rstd * g4.x + B4.x);
  r.y = silu_f(dy * rstd * g4.y + B4.y);
  r.z = silu_f(dz * rstd * g4.z + B4.z);
  r.w = silu_f(dw * rstd * g4.w + B4.w);
  st4(xout + (size_t)b * 2048 + head * 1024 + n, r);
}

// ---------------------------------------------------------------------------
// K_samp: per-b block. Reduce out-layer partials -> logits; wave-parallel
// gumbel-max sampling (32-lane groups, shfl reduce); prior one-hot -> feat;
// posterior one-hot -> gW row-gather + act GEMV + LN + SiLU -> hcat xg-half.
// ---------------------------------------------------------------------------
__global__ __launch_bounds__(256) void k_samp(
    const float* __restrict__ part3,
    const float* __restrict__ qbo, const float* __restrict__ pbo,
    const float* __restrict__ g_prior, const float* __restrict__ g_post,
    const float* __restrict__ actions, const float* __restrict__ gW,
    const float* __restrict__ gb, const float* __restrict__ gg,
    const float* __restrict__ gB, float* __restrict__ out,
    float* __restrict__ hcat, int i, int do_q, int do_p) {
  const int b = blockIdx.x, tid = threadIdx.x;
  const int lane = tid & 63, wave = tid >> 6;
  __shared__ float lq[1024], lp[1024];
  __shared__ int idxp[SN];
  __shared__ float sm[8];
  const int n = tid * 4;

  if (do_q) {
    float4 acc = ld4(qbo + n);
#pragma unroll
    for (int v = 0; v < 32; ++v)
      add4(acc, ld4(part3 + ((size_t)v * 16 + b) * 2048 + n));
    st4(lq + n, acc);
  }
  if (do_p) {
    float4 acc = ld4(pbo + n);
#pragma unroll
    for (int v = 0; v < 32; ++v)
      add4(acc, ld4(part3 + ((size_t)v * 16 + b) * 2048 + 1024 + n));
    st4(lp + n, acc);
  }
  __syncthreads();

  const int c = tid & 31, grp = tid >> 5;  // 8 groups of 32 lanes
#pragma unroll
  for (int pass = 0; pass < 4; ++pass) {
    const int s_ = pass * 8 + grp;
    if (do_q) {  // prior sample for step i-1 -> one-hot into feat
      float l = lq[s_ * CN + c];
      float m = l;
#pragma unroll
      for (int mk = 1; mk <= 16; mk <<= 1) m = fmaxf(m, __shfl_xor(m, mk));
      float e = expf(l - m);
      float Z = e;
#pragma unroll
      for (int mk = 1; mk <= 16; mk <<= 1) Z += __shfl_xor(Z, mk);
      float p = 0.99f * (e / Z) + UNI;
      float sc = logf(p) + g_prior[(((size_t)(i - 1) * BB + b) * SN + s_) * CN + c];
      float bs = sc; int bc = c;
#pragma unroll
      for (int mk = 1; mk <= 16; mk <<= 1) {
        float os = __shfl_xor(bs, mk);
        int oc = __shfl_xor(bc, mk);
        if (os > bs || (os == bs && oc < bc)) { bs = os; bc = oc; }
      }
      out[((size_t)b * TT + (i - 1)) * FEAT + DD + s_ * CN + c] =
          (c == bc) ? ((1.0f - p) + p) : 0.0f;
    }
    if (do_p) {  // posterior sample for step i -> idxp
      float l = lp[s_ * CN + c];
      float m = l;
#pragma unroll
      for (int mk = 1; mk <= 16; mk <<= 1) m = fmaxf(m, __shfl_xor(m, mk));
      float e = expf(l - m);
      float Z = e;
#pragma unroll
      for (int mk = 1; mk <= 16; mk <<= 1) Z += __shfl_xor(Z, mk);
      float p = 0.99f * (e / Z) + UNI;
      float sc = logf(p) + g_post[(((size_t)i * BB + b) * SN + s_) * CN + c];
      float bs = sc; int bc = c;
#pragma unroll
      for (int mk = 1; mk <= 16; mk <<= 1) {
        float os = __shfl_xor(bs, mk);
        int oc = __shfl_xor(bc, mk);
        if (os > bs || (os == bs && oc < bc)) { bs = os; bc = oc; }
      }
      if (c == 0) idxp[s_] = bc;
    }
  }
  __syncthreads();

  if (do_p) {  // one-hot row gather + action GEMV + LN + SiLU -> xg (hcat)
    float av[AN];
#pragma unroll
    for (int aa = 0; aa < AN; ++aa)
      av[aa] = actions[((size_t)b * TT + i) * AN + aa];
    float4 acc = ld4(gb + n);
#pragma unroll
    for (int ss = 0; ss < SN; ++ss) {
      const int row = ss * CN + idxp[ss];
      add4(acc, ld4(gW + (size_t)row * HH + n));
    }
#pragma unroll
    for (int aa = 0; aa < AN; ++aa)
      fma4(acc, av[aa], ld4(gW + (size_t)(SCN + aa) * HH + n));
    float s = wave_sum(acc.x + acc.y + acc.z + acc.w);
    if (lane == 0) sm[wave] = s;
    __syncthreads();
    const float mean = (sm[0] + sm[1] + sm[2] + sm[3]) * (1.0f / 1024.0f);
    float dx = acc.x - mean, dy = acc.y - mean, dz = acc.z - mean, dw = acc.w - mean;
    float vs = wave_sum(dx * dx + dy * dy + dz * dz + dw * dw);
    if (lane == 0) sm[4 + wave] = vs;
    __syncthreads();
    const float rstd = 1.0f / sqrtf((sm[4] + sm[5] + sm[6] + sm[7]) * (1.0f / 1024.0f) + 1e-5f);
    float4 g4 = ld4(gg + n), B4 = ld4(gB + n);
    float4 r;
    r.x = silu_f(dx * rstd * g4.x + B4.x);
    r.y = silu_f(dy * rstd * g4.y + B4.y);
    r.z = silu_f(dz * rstd * g4.z + B4.z);
    r.w = silu_f(dw * rstd * g4.w + B4.w);
    st4(hcat + (size_t)b * FEAT + n, r);
  }
}

// ---------------------------------------------------------------------------
// K_g: GRU gate GEMMs. h = hcat[b][0:5120] (xg|deter), K=5120, N=4096, z & c.
// grid 512: v=bid&31 (kchunk 160), ntile=bid>>5 (16). partG[v][2][16][4096].
// ---------------------------------------------------------------------------
__global__ __launch_bounds__(256) void k_g(
    const float* __restrict__ hcat, const float* __restrict__ gWz,
    const float* __restrict__ gWc, float* __restrict__ partG) {
  const int bid = blockIdx.x;
  const int v = bid & 31, nt = bid >> 5;
  const int lane = threadIdx.x & 63, wave = threadIdx.x >> 6, b0 = wave * 4;
  const int n = nt * 256 + lane * 4;
  const float* wz = gWz + (size_t)(v * 160) * DD + n;
  const float* wc = gWc + (size_t)(v * 160) * DD + n;
  const float* ap = hcat + (size_t)b0 * FEAT + v * 160;
  float4 az0 = z4(), az1 = z4(), az2 = z4(), az3 = z4();
  float4 ac0 = z4(), ac1 = z4(), ac2 = z4(), ac3 = z4();
#pragma unroll 2
  for (int k = 0; k < 160; k += 4) {
    float4 x0 = ld4(ap + k);
    float4 x1 = ld4(ap + FEAT + k);
    float4 x2 = ld4(ap + 2 * FEAT + k);
    float4 x3 = ld4(ap + 3 * FEAT + k);
    float4 wz0 = ld4(wz + (size_t)(k + 0) * DD);
    float4 wz1 = ld4(wz + (size_t)(k + 1) * DD);
    float4 wz2 = ld4(wz + (size_t)(k + 2) * DD);
    float4 wz3 = ld4(wz + (size_t)(k + 3) * DD);
    float4 wc0 = ld4(wc + (size_t)(k + 0) * DD);
    float4 wc1 = ld4(wc + (size_t)(k + 1) * DD);
    float4 wc2 = ld4(wc + (size_t)(k + 2) * DD);
    float4 wc3 = ld4(wc + (size_t)(k + 3) * DD);
    fma4(az0, x0.x, wz0); fma4(az1, x1.x, wz0); fma4(az2, x2.x, wz0); fma4(az3, x3.x, wz0);
    fma4(az0, x0.y, wz1); fma4(az1, x1.y, wz1); fma4(az2, x2.y, wz1); fma4(az3, x3.y, wz1);
    fma4(az0, x0.z, wz2); fma4(az1, x1.z, wz2); fma4(az2, x2.z, wz2); fma4(az3, x3.z, wz2);
    fma4(az0, x0.w, wz3); fma4(az1, x1.w, wz3); fma4(az2, x2.w, wz3); fma4(az3, x3.w, wz3);
    fma4(ac0, x0.x, wc0); fma4(ac1, x1.x, wc0); fma4(ac2, x2.x, wc0); fma4(ac3, x3.x, wc0);
    fma4(ac0, x0.y, wc1); fma4(ac1, x1.y, wc1); fma4(ac2, x2.y, wc1); fma4(ac3, x3.y, wc1);
    fma4(ac0, x0.z, wc2); fma4(ac1, x1.z, wc2); fma4(ac2, x2.z, wc2); fma4(ac3, x3.z, wc2);
    fma4(ac0, x0.w, wc3); fma4(ac1, x1.w, wc3); fma4(ac2, x2.w, wc3); fma4(ac3, x3.w, wc3);
  }
  float* oz = partG + ((size_t)(v * 2 + 0) * 16 + b0) * DD + n;
  float* oc = partG + ((size_t)(v * 2 + 1) * 16 + b0) * DD + n;
  st4(oz, az0); st4(oz + DD, az1); st4(oz + 2 * DD, az2); st4(oz + 3 * DD, az3);
  st4(oc, ac0); st4(oc + DD, ac1); st4(oc + 2 * DD, ac2); st4(oc + 3 * DD, ac3);
}

// ---------------------------------------------------------------------------
// K_r: reduce GRU partials; deter = (1-z)*deter + z*tanh(c); write hcat
// deter-half + feat. grid 256: bid>>4=b, bid&15=nchunk(256).
// ---------------------------------------------------------------------------
__global__ __launch_bounds__(256) void k_r(
    const float* __restrict__ partG, const float* __restrict__ gbz,
    const float* __restrict__ gbc, float* __restrict__ hcat,
    float* __restrict__ out, int i) {
  const int b = blockIdx.x >> 4, ch = blockIdx.x & 15;
  const int n = ch * 256 + threadIdx.x;
  float zs = gbz[n], cs = gbc[n];
#pragma unroll 8
  for (int v = 0; v < 32; ++v) {
    zs += partG[((size_t)(v * 2 + 0) * 16 + b) * DD + n];
    cs += partG[((size_t)(v * 2 + 1) * 16 + b) * DD + n];
  }
  const float z = 1.0f / (1.0f + expf(-zs));
  const float cd = tanhf(cs);
  float* hp = hcat + (size_t)b * FEAT + 1024 + n;
  const float dn = (1.0f - z) * hp[0] + z * cd;
  hp[0] = dn;
  out[((size_t)b * TT + i) * FEAT + n] = dn;
}

// ---------------------------------------------------------------------------
extern "C" void kernel_launch(void* const* d_in, const int* in_sizes, int n_in,
                              void* d_out, int out_size, void* d_ws,
                              size_t ws_size, hipStream_t stream) {
  (void)in_sizes; (void)n_in; (void)out_size; (void)ws_size;
  const float* tokens  = (const float*)d_in[0];
  const float* actions = (const float*)d_in[1];
  const float* g_post  = (const float*)d_in[2];
  const float* g_prior = (const float*)d_in[3];
  const float* pW1 = (const float*)d_in[4];
  const float* pb1 = (const float*)d_in[5];
  const float* pg1 = (const float*)d_in[6];
  const float* pB1 = (const float*)d_in[7];
  const float* pW2 = (const float*)d_in[8];
  const float* pb2 = (const float*)d_in[9];
  const float* pg2 = (const float*)d_in[10];
  const float* pB2 = (const float*)d_in[11];
  const float* pWo = (const float*)d_in[12];
  const float* pbo = (const float*)d_in[13];
  const float* qW1 = (const float*)d_in[14];
  const float* qb1 = (const float*)d_in[15];
  const float* qg1 = (const float*)d_in[16];
  const float* qB1 = (const float*)d_in[17];
  const float* qW2 = (const float*)d_in[18];
  const float* qb2 = (const float*)d_in[19];
  const float* qg2 = (const float*)d_in[20];
  const float* qB2 = (const float*)d_in[21];
  const float* qWo = (const float*)d_in[22];
  const float* qbo = (const float*)d_in[23];
  const float* gW  = (const float*)d_in[24];
  const float* gb  = (const float*)d_in[25];
  const float* gg  = (const float*)d_in[26];
  const float* gB  = (const float*)d_in[27];
  const float* gWz = (const float*)d_in[28];
  const float* gbz = (const float*)d_in[29];
  const float* gWc = (const float*)d_in[30];
  const float* gbc = (const float*)d_in[31];
  float* out = (float*)d_out;

  // Workspace layout (floats); part1 and partG share the 'big' region
  // (disjoint lifetimes within a step: part1 dies at k_red1, partG born at k_g).
  float* ws    = (float*)d_ws;
  float* y1tok = ws + 0;         // [64][16][1024] = 1,048,576
  float* part2 = ws + 1048576;   // [32][16][2048] = 1,048,576 (mid1 & mid2 share)
  float* x1    = ws + 2097152;   // [16][2048]
  float* x2    = ws + 2129920;   // [16][2048]
  float* hcat  = ws + 2162688;   // [16][5120] (xg | deter)
  float* big   = ws + 2244608;   // max(part1 2,097,152, partG 4,194,304)
  float* part1 = big;            // [64][16][2048]
  float* partG = big;            // [32][2][16][4096]
  // total = 6,438,912 floats ~= 24.6 MiB

  k0_pre<<<256, 256, 0, stream>>>(tokens, pW1, pb1, y1tok, hcat);

  for (int i = 0; i <= TT; ++i) {
    const int do_q = (i >= 1) ? 1 : 0;
    const int do_p = (i <= TT - 1) ? 1 : 0;
    const float* ytokrow = y1tok + (size_t)((i <= 63) ? i : 63) * 16 * HH;

    k_qp1<<<512, 256, 0, stream>>>(hcat, qW1, pW1, part1, do_q, do_p);
    k_red<64><<<32, 256, 0, stream>>>(part1, qb1, pb1, ytokrow,
                                      qg1, qB1, pg1, pB1, x1, do_q, do_p);
    k_mid<<<256, 256, 0, stream>>>(x1, qW2, pW2, part2, do_q, do_p);
    k_red<32><<<32, 256, 0, stream>>>(part2, qb2, pb2, nullptr,
                                      qg2, qB2, pg2, pB2, x2, do_q, do_p);
    k_mid<<<256, 256, 0, stream>>>(x2, qWo, pWo, part2, do_q, do_p);
    k_samp<<<16, 256, 0, stream>>>(part2, qbo, pbo, g_prior, g_post, actions,
                                   gW, gb, gg, gB, out, hcat, i, do_q, do_p);
    if (do_p) {
      k_g<<<512, 256, 0, stream>>>(hcat, gWz, gWc, partG);
      k_r<<<256, 256, 0, stream>>>(partG, gbz, gbc, hcat, out, i);
    }
  }
}